// Round 3
// baseline (761.172 us; speedup 1.0000x reference)
//
#include <hip/hip_runtime.h>

typedef short bf16x8 __attribute__((ext_vector_type(8)));
typedef float f32x4 __attribute__((ext_vector_type(4)));

// ---------- helpers ----------
__device__ __forceinline__ ushort f2bf(float f) {
  union { float f; unsigned u; } x; x.f = f;
  unsigned r = x.u + 0x7fffu + ((x.u >> 16) & 1u);  // RNE
  return (ushort)(r >> 16);
}
__device__ __forceinline__ float bf2f(ushort u) {
  union { unsigned u; float f; } x; x.u = ((unsigned)u) << 16; return x.f;
}
__device__ __forceinline__ void load_lds16(const void* g, void* l) {
  __builtin_amdgcn_global_load_lds((const __attribute__((address_space(1))) void*)g,
                                   (__attribute__((address_space(3))) void*)l, 16, 0, 0);
}
// asm ds_read_b128: hides the LDS RAW dependence on global_load_lds from the
// compiler so it cannot insert conservative vmcnt(0) drains before read bursts.
// Ordering is enforced ONLY by our explicit barriers + lgkmcnt(0)+sched_barrier.
typedef __attribute__((address_space(3))) const ushort* lds_cp;
__device__ __forceinline__ bf16x8 dsr16(const ushort* p) {
  bf16x8 r;
  asm volatile("ds_read_b128 %0, %1" : "=v"(r) : "v"((lds_cp)p));
  return r;
}
__device__ __forceinline__ void store_out(float* p, float v) { *p = v; }
__device__ __forceinline__ void store_out(ushort* p, float v) { *p = f2bf(v); }

// ---------- fp32 -> bf16 cast ----------
__global__ __launch_bounds__(256) void cast_kernel(const float* __restrict__ in,
                                                   ushort* __restrict__ out, int n4) {
  int i = blockIdx.x * 256 + threadIdx.x;
  if (i < n4) {
    float4 v = ((const float4*)in)[i];
    ushort4 o;
    o.x = f2bf(v.x); o.y = f2bf(v.y); o.z = f2bf(v.z); o.w = f2bf(v.w);
    ((ushort4*)out)[i] = o;
  }
}

// ---------- 256x256 NT GEMM, 2-super-phase / 3-sync K-loop ----------
// C[M,N] = A[M,K] * B[N,K]^T, bf16 in, fp32 acc. BK=64, 512 thr = 8 waves
// (2M x 4N), per-wave 128x64 out. LDS 128 KiB: double-buffered 256x64 tiles.
// LDS[row][chunk16B] = G[row][chunk ^ (row&7)] -> conflict-free b128 reads.
// Per K-tile t (only 3 syncs, 2 lgkm drains -> waves can slip & cross-cover):
//   boundary: vmcnt(4) [vmcnt(0) at NT-1]; s_barrier        (buf t published)
//   SP1: read B all (8) + A-QM0 (8) | stage A(t+1) both halves (opp. buffer)
//        lgkm0 ; MID-BAR (all waves done reading B[t]) ; stage B(t+2)
//        MFMA Q(0,0) Q(0,1)  [32]
//   SP2: read A-QM1 (8) ; lgkm0 ; MFMA Q(1,0) Q(1,1)  [32]
// Hazard audit: A(t+1) -> opposite buffer (all its reads finished before each
// wave's previous boundary arrival). B(t+2) -> B-region of buf[t], written
// only after MID-BAR certifies all waves' B[t] reads complete; A1 reads touch
// the disjoint A-region. vmcnt ledger: at boundary of t, outstanding =
// B(t)[mid t-2, oldest] A(t)[top t-1] B(t+1)[mid t-1, newest]; vmcnt(4)
// retires B(t)+A(t), keeps B(t+1). Prologue stages A(0),B(0),B(1) so t=0
// obeys the same rule. vmcnt(0) only at t==NT-1.
#define PBAR() do { asm volatile("" ::: "memory"); __builtin_amdgcn_s_barrier(); \
                    asm volatile("" ::: "memory"); } while (0)
#define WAITL() do { asm volatile("s_waitcnt lgkmcnt(0)" ::: "memory"); \
                     __builtin_amdgcn_sched_barrier(0); } while (0)

template <typename OutT>
__global__ __launch_bounds__(512) void gemm256(const ushort* __restrict__ A,
                                               const ushort* __restrict__ B,
                                               OutT* __restrict__ C,
                                               int M, int N, int K) {
  __shared__ ushort As[2][256 * 64];
  __shared__ ushort Bs[2][256 * 64];
  const int tid = threadIdx.x;
  const int wave = tid >> 6, lane = tid & 63;
  const int quad = lane >> 4, lx = lane & 15;
  const int wr = wave >> 2, wc = wave & 3;
  const int m0 = blockIdx.y * 256, n0 = blockIdx.x * 256;
  const int NT = K >> 6;
  const int sgrow = lane >> 3;                 // row within 8-row group
  const int sgchunk = ((lane & 7) ^ sgrow) * 8;  // swizzled global chunk (elems)

  f32x4 acc[8][4] = {};
  bf16x8 af[4][2], bfr[4][2];

#define STAGE_A(T, H)                                                         \
  do {                                                                        \
    _Pragma("unroll") for (int i_ = 0; i_ < 2; ++i_) {                        \
      const int rg_ = (H) * 128 + wave * 16 + i_ * 8;                         \
      load_lds16(A + (size_t)(m0 + rg_ + sgrow) * K + (T) * 64 + sgchunk,     \
                 &As[(T) & 1][rg_ * 64]);                                     \
    }                                                                         \
  } while (0)
#define STAGE_B(T, H)                                                         \
  do {                                                                        \
    _Pragma("unroll") for (int i_ = 0; i_ < 2; ++i_) {                        \
      const int rg_ = (H) * 128 + wave * 16 + i_ * 8;                         \
      load_lds16(B + (size_t)(n0 + rg_ + sgrow) * K + (T) * 64 + sgchunk,     \
                 &Bs[(T) & 1][rg_ * 64]);                                     \
    }                                                                         \
  } while (0)
// frag reads: A-frag lane row = frag_row0 + (lane&15), k = s*32 + quad*8 + [0,8)
// chunk = s*4+quad, XOR-unswizzle with row&7 (= lx&7 since rows are 16-aligned)
#define READ_A(QM)                                                            \
  _Pragma("unroll") for (int mm = 0; mm < 4; ++mm)                            \
  _Pragma("unroll") for (int s = 0; s < 2; ++s)                               \
    af[mm][s] = dsr16(curA + (wr * 128 + ((QM) * 4 + mm) * 16 + lx) * 64      \
                      + (((s * 4 + quad) ^ (lx & 7)) * 8));
#define READ_B(NLO)                                                           \
  _Pragma("unroll") for (int nn = 0; nn < 2; ++nn)                            \
  _Pragma("unroll") for (int s = 0; s < 2; ++s)                               \
    bfr[(NLO) + nn][s] = dsr16(curB + (wc * 64 + ((NLO) + nn) * 16 + lx) * 64 \
                               + (((s * 4 + quad) ^ (lx & 7)) * 8));
// k-slice OUTERMOST: 8 independent MFMAs between accumulator reuses
#define MFMA_Q(QM, QN)                                                        \
  __builtin_amdgcn_s_setprio(1);                                              \
  _Pragma("unroll") for (int s = 0; s < 2; ++s)                               \
  _Pragma("unroll") for (int mm = 0; mm < 4; ++mm)                            \
  _Pragma("unroll") for (int nn = 0; nn < 2; ++nn)                            \
    acc[(QM) * 4 + mm][(QN) * 2 + nn] = __builtin_amdgcn_mfma_f32_16x16x32_bf16( \
        af[mm][s], bfr[(QN) * 2 + nn][s], acc[(QM) * 4 + mm][(QN) * 2 + nn], 0, 0, 0); \
  __builtin_amdgcn_s_setprio(0);

  // prologue: A(0) both halves, B(0) both halves, B(1) both halves
  STAGE_A(0, 0); STAGE_A(0, 1); STAGE_B(0, 0); STAGE_B(0, 1);
  if (NT > 1) { STAGE_B(1, 0); STAGE_B(1, 1); }

  for (int t = 0; t < NT; ++t) {
    asm volatile("" ::: "memory");
    if (t == NT - 1) { asm volatile("s_waitcnt vmcnt(0)" ::: "memory"); }
    else             { asm volatile("s_waitcnt vmcnt(4)" ::: "memory"); }
    __builtin_amdgcn_s_barrier();
    asm volatile("" ::: "memory");
    const ushort* curA = As[t & 1];
    const ushort* curB = Bs[t & 1];
    // super-phase 1: all B frags + A-QM0 frags; stage next A (opposite buf)
    READ_A(0); READ_B(0); READ_B(2);
    if (t + 1 < NT) { STAGE_A(t + 1, 0); STAGE_A(t + 1, 1); }
    WAITL();
    PBAR();  // all waves done reading B[t] -> B-region of buf[t] reusable
    if (t + 2 < NT) { STAGE_B(t + 2, 0); STAGE_B(t + 2, 1); }
    MFMA_Q(0, 0);
    MFMA_Q(0, 1);
    // super-phase 2: A-QM1 frags (B stays in registers)
    READ_A(1);
    WAITL();
    MFMA_Q(1, 0);
    MFMA_Q(1, 1);
  }

  // epilogue: 16x16 C/D layout col=lane&15, row=(lane>>4)*4+reg (m89/m91)
#pragma unroll
  for (int m = 0; m < 8; ++m)
#pragma unroll
    for (int n = 0; n < 4; ++n)
#pragma unroll
      for (int r = 0; r < 4; ++r) {
        const int row = m0 + wr * 128 + m * 16 + quad * 4 + r;
        const int col = n0 + wc * 64 + n * 16 + lx;
        store_out(C + (size_t)row * N + col, acc[m][n][r]);
      }
#undef STAGE_A
#undef STAGE_B
#undef READ_A
#undef READ_B
#undef MFMA_Q
}

// ---------- RoPE in-place on bf16 qkv ----------
__global__ __launch_bounds__(256) void rope_kernel(const int* __restrict__ pos,
                                                   ushort* __restrict__ qkv) {
  const int rid = blockIdx.x * 4 + (threadIdx.x >> 6);
  const int d = threadIdx.x & 63;
  const int t = rid / 40;
  const int hh = rid - t * 40;
  ushort* p = qkv + (size_t)t * 6144 + (hh < 32 ? hh * 128 : 4096 + (hh - 32) * 128);
  const float inv_freq = powf(10000.0f, -(float)d * (1.0f / 64.0f));
  const float fr = (float)pos[t] * inv_freq;
  float sn, cs;
  sincosf(fr, &sn, &cs);
  const float x1 = bf2f(p[d]);
  const float x2 = bf2f(p[d + 64]);
  p[d] = f2bf(x1 * cs - x2 * sn);
  p[d + 64] = f2bf(x2 * cs + x1 * sn);
}

// ---------- fused flash attention (bf16 MFMA, causal GQA) ----------
// grid: 1024 = B(4) * H(32) * PAIR(8). Block = 256 thr = 4 waves.
// Block processes q-tiles (pair) and (15-pair) of 64 rows -> 17 k-tiles each.
__global__ __launch_bounds__(256) void attn_fused(const ushort* __restrict__ qkv,
                                                  ushort* __restrict__ outb) {
  const int bid = blockIdx.x;
  const int pair = bid & 7;
  const int h = (bid >> 3) & 31;
  const int b = bid >> 8;
  const int kvh = h >> 2;                  // G = 4
  const int tid = threadIdx.x, wave = tid >> 6, lane = tid & 63;
  const int quad = lane >> 4, lx = lane & 15;

  __shared__ ushort Ks[64 * 128];   // [key][d], chunk ^= key&7
  __shared__ ushort Vt[128 * 64];   // [d][key], chunk ^= d&7
  __shared__ ushort Ps[64 * 64];    // [qrow][key], chunk ^= qrow&7

  const size_t tb = (size_t)b * 1024;
  const float scale = 0.08838834764831843f;  // 1/sqrt(128)

#pragma unroll
  for (int phase = 0; phase < 2; ++phase) {
    const int qt64 = phase ? (15 - pair) : pair;
    const int qrow0 = qt64 * 64 + wave * 16;

    bf16x8 qf[4];
#pragma unroll
    for (int ks = 0; ks < 4; ++ks)
      qf[ks] = *(const bf16x8*)(qkv + (tb + qrow0 + lx) * 6144 + h * 128 + ks * 32 + quad * 8);

    f32x4 o[8] = {};
    float mst[4], lst[4];
#pragma unroll
    for (int r = 0; r < 4; ++r) { mst[r] = -1e30f; lst[r] = 0.f; }

    const int nkt = qt64 + 1;
    for (int it = 0; it < nkt; ++it) {
      const int kb = it * 64;
      __syncthreads();
#pragma unroll
      for (int i = 0; i < 4; ++i) {
        const int rg = wave * 16 + i * 4;
        const int row = rg + quad;
        load_lds16(qkv + (tb + kb + row) * 6144 + 4096 + kvh * 128 + ((lx ^ (row & 7)) * 8),
                   Ks + rg * 128);
      }
      {
        const ushort* vp = qkv + (tb + kb + lane) * 6144 + 5120 + kvh * 128 + wave * 32;
#pragma unroll
        for (int c = 0; c < 4; ++c) {
          bf16x8 v8 = *(const bf16x8*)(vp + c * 8);
#pragma unroll
          for (int e = 0; e < 8; ++e) {
            const int d = wave * 32 + c * 8 + e;
            Vt[d * 64 + (((lane >> 3) ^ (d & 7)) * 8) + (lane & 7)] = (ushort)v8[e];
          }
        }
      }
      __syncthreads();

      f32x4 s[4] = {};
#pragma unroll
      for (int ks = 0; ks < 4; ++ks) {
        bf16x8 kf[4];
#pragma unroll
        for (int kt = 0; kt < 4; ++kt)
          kf[kt] = *(const bf16x8*)(Ks + (kt * 16 + lx) * 128 + (((ks * 4 + quad) ^ (lx & 7)) * 8));
#pragma unroll
        for (int kt = 0; kt < 4; ++kt)
          s[kt] = __builtin_amdgcn_mfma_f32_16x16x32_bf16(qf[ks], kf[kt], s[kt], 0, 0, 0);
      }

      const bool diag = (kb + 63 > qrow0);
#pragma unroll
      for (int r = 0; r < 4; ++r) {
        const int row = qrow0 + quad * 4 + r;
        float mx = -1e30f;
#pragma unroll
        for (int kt = 0; kt < 4; ++kt) {
          float sv = s[kt][r] * scale;
          if (diag && (kb + kt * 16 + lx > row)) sv = -1e30f;
          s[kt][r] = sv;
          mx = fmaxf(mx, sv);
        }
        mx = fmaxf(mx, __shfl_xor(mx, 1));
        mx = fmaxf(mx, __shfl_xor(mx, 2));
        mx = fmaxf(mx, __shfl_xor(mx, 4));
        mx = fmaxf(mx, __shfl_xor(mx, 8));
        const float mnew = fmaxf(mst[r], mx);
        const float alpha = __expf(mst[r] - mnew);
        mst[r] = mnew;
        float rs = 0.f;
#pragma unroll
        for (int kt = 0; kt < 4; ++kt) {
          const float pv = __expf(s[kt][r] - mnew);
          s[kt][r] = pv;
          rs += pv;
        }
        rs += __shfl_xor(rs, 1); rs += __shfl_xor(rs, 2);
        rs += __shfl_xor(rs, 4); rs += __shfl_xor(rs, 8);
        lst[r] = lst[r] * alpha + rs;
#pragma unroll
        for (int dt = 0; dt < 8; ++dt) o[dt][r] *= alpha;
        const int prow = wave * 16 + quad * 4 + r;
#pragma unroll
        for (int kt = 0; kt < 4; ++kt)
          Ps[prow * 64 + (((kt * 2 + (lx >> 3)) ^ (prow & 7)) * 8) + (lx & 7)] = f2bf(s[kt][r]);
      }
      __syncthreads();

#pragma unroll
      for (int ks2 = 0; ks2 < 2; ++ks2) {
        const int prow = wave * 16 + lx;
        bf16x8 pf = *(const bf16x8*)(Ps + prow * 64 + (((ks2 * 4 + quad) ^ (lx & 7)) * 8));
#pragma unroll
        for (int dt = 0; dt < 8; ++dt) {
          bf16x8 vf = *(const bf16x8*)(Vt + (dt * 16 + lx) * 64 + (((ks2 * 4 + quad) ^ (lx & 7)) * 8));
          o[dt] = __builtin_amdgcn_mfma_f32_16x16x32_bf16(pf, vf, o[dt], 0, 0, 0);
        }
      }
    }

#pragma unroll
    for (int r = 0; r < 4; ++r) {
      const float inv = 1.f / lst[r];
      const int row = qrow0 + quad * 4 + r;
#pragma unroll
      for (int dt = 0; dt < 8; ++dt)
        outb[(tb + row) * 4096 + h * 128 + dt * 16 + lx] = f2bf(o[dt][r] * inv);
    }
  }
}

// ---------- launch ----------
extern "C" void kernel_launch(void* const* d_in, const int* in_sizes, int n_in,
                              void* d_out, int out_size, void* d_ws, size_t ws_size,
                              hipStream_t stream) {
  const int* positions = (const int*)d_in[0];
  const float* hidden  = (const float*)d_in[1];
  const float* w_qkv   = (const float*)d_in[2];
  const float* w_dense = (const float*)d_in[3];
  float* out = (float*)d_out;

  ushort* hidden_bf = (ushort*)d_ws;                         // 4096*4096
  ushort* wqkv_bf   = hidden_bf + (size_t)16777216;          // 6144*4096
  ushort* wdense_bf = wqkv_bf   + (size_t)25165824;          // 4096*4096
  ushort* qkv_bf    = wdense_bf + (size_t)16777216;          // 4096*6144
  ushort* attn_bf   = qkv_bf    + (size_t)25165824;          // 4096*4096

  cast_kernel<<<16384, 256, 0, stream>>>(hidden,  hidden_bf, 4194304);
  cast_kernel<<<24576, 256, 0, stream>>>(w_qkv,   wqkv_bf,   6291456);
  cast_kernel<<<16384, 256, 0, stream>>>(w_dense, wdense_bf, 4194304);

  gemm256<ushort><<<dim3(24, 16), 512, 0, stream>>>(hidden_bf, wqkv_bf, qkv_bf, 4096, 6144, 4096);

  rope_kernel<<<40960, 256, 0, stream>>>(positions, qkv_bf);

  attn_fused<<<1024, 256, 0, stream>>>(qkv_bf, attn_bf);

  gemm256<float><<<dim3(16, 16), 512, 0, stream>>>(attn_bf, wdense_bf, out, 4096, 4096, 4096);
}

// Round 4
// 759.357 us; speedup vs baseline: 1.0024x; 1.0024x over previous
//
#include <hip/hip_runtime.h>

typedef short bf16x8 __attribute__((ext_vector_type(8)));
typedef float f32x4 __attribute__((ext_vector_type(4)));

// ---------- helpers ----------
__device__ __forceinline__ ushort f2bf(float f) {
  union { float f; unsigned u; } x; x.f = f;
  unsigned r = x.u + 0x7fffu + ((x.u >> 16) & 1u);  // RNE
  return (ushort)(r >> 16);
}
__device__ __forceinline__ float bf2f(ushort u) {
  union { unsigned u; float f; } x; x.u = ((unsigned)u) << 16; return x.f;
}
__device__ __forceinline__ void load_lds16(const void* g, void* l) {
  __builtin_amdgcn_global_load_lds((const __attribute__((address_space(1))) void*)g,
                                   (__attribute__((address_space(3))) void*)l, 16, 0, 0);
}
// asm ds_read_b128: hides the LDS RAW dependence on global_load_lds from the
// compiler (no conservative vmcnt drains). Ordering enforced ONLY by explicit
// barriers + counted lgkmcnt + sched_barrier fences.
typedef __attribute__((address_space(3))) const ushort* lds_cp;
__device__ __forceinline__ bf16x8 dsr16(const ushort* p) {
  bf16x8 r;
  asm volatile("ds_read_b128 %0, %1" : "=v"(r) : "v"((lds_cp)p));
  return r;
}
__device__ __forceinline__ void store_out(float* p, float v) { *p = v; }
__device__ __forceinline__ void store_out(ushort* p, float v) { *p = f2bf(v); }

// ---------- fp32 -> bf16 cast ----------
__global__ __launch_bounds__(256) void cast_kernel(const float* __restrict__ in,
                                                   ushort* __restrict__ out, int n4) {
  int i = blockIdx.x * 256 + threadIdx.x;
  if (i < n4) {
    float4 v = ((const float4*)in)[i];
    ushort4 o;
    o.x = f2bf(v.x); o.y = f2bf(v.y); o.z = f2bf(v.z); o.w = f2bf(v.w);
    ((ushort4*)out)[i] = o;
  }
}

// ---------- 256x256 NT GEMM, counted-lgkm JIT pipeline ----------
// C[M,N] = A[M,K] * B[N,K]^T, bf16 in, fp32 acc. BK=64, 512 thr = 8 waves
// (2M x 4N), per-wave 128x64 out. LDS 128 KiB: double-buffered 256x64 tiles.
// LDS[row][chunk16B] = G[row][chunk ^ (row&7)] -> conflict-free b128 reads.
//
// Per K-tile t (2 barriers, 4 COUNTED lgkm waits, counted vmcnt at boundary):
//   boundary: vmcnt(4) [vmcnt(0) at NT-1]; s_barrier      (buf t published)
//   G1: afA=A[m0-3,s0](4) bfA=B[n0-3,s0](4)   G2: afB=A[m4-7,s0](4)
//   stage A(t+1) both halves (opposite buffer)
//   lgkm(4)  -> Q1: afA x bfA (16 MFMA)        | port streams G2,G3 under Q1
//   G3: afA=A[m0-3,s1](4) bfB=B[n0-3,s1](4)
//   lgkm(8)  -> Q2: afB x bfA (16 MFMA)
//   G4: afB=A[m4-7,s1](4)
//   lgkm(4)  [G3 done => ALL B-reads of tile t done]
//   MID-BAR  -> stage B(t+2) into B-region of buf[t]
//   Q3: afA x bfB ; lgkm(0) -> Q4: afB x bfB
// Hazards: A(t+1) -> opposite buffer; all its reads finished before each
// wave's previous boundary arrival. B(t+2) -> buf[t] B-region, written only
// after MID-BAR certifies all waves' B[t] reads complete; A-region reads
// (G4) are disjoint. vmcnt ledger: at boundary of t, in program order
// B(t)[mid t-2] .. A(t)[top t-1] .. B(t+1)[mid t-1, 4 newest]; vmcnt(4)
// retires A(t)+B(t), keeps B(t+1). Prologue stages A(0),B(0),B(1) so t=0
// obeys the same rule. lgkm ledger (ds_reads only; global_load_lds counts
// on vmcnt): after G1+G2 out<=12, lgkm(4) => G1 done; after G3 out<=12,
// lgkm(8) => G2 done; after G4 out<=12, lgkm(4) => G3 done; lgkm(0) => G4.
#define PBAR() do { asm volatile("" ::: "memory"); __builtin_amdgcn_s_barrier(); \
                    asm volatile("" ::: "memory"); } while (0)
#define WAITK(n) do { asm volatile("s_waitcnt lgkmcnt(" #n ")" ::: "memory"); \
                      __builtin_amdgcn_sched_barrier(0); } while (0)

template <typename OutT>
__global__ __launch_bounds__(512) void gemm256(const ushort* __restrict__ A,
                                               const ushort* __restrict__ B,
                                               OutT* __restrict__ C,
                                               int M, int N, int K) {
  __shared__ ushort As[2][256 * 64];
  __shared__ ushort Bs[2][256 * 64];
  const int tid = threadIdx.x;
  const int wave = tid >> 6, lane = tid & 63;
  const int quad = lane >> 4, lx = lane & 15;
  const int wr = wave >> 2, wc = wave & 3;
  const int m0 = blockIdx.y * 256, n0 = blockIdx.x * 256;
  const int NT = K >> 6;
  const int sgrow = lane >> 3;                 // row within 8-row group
  const int sgchunk = ((lane & 7) ^ sgrow) * 8;  // swizzled global chunk (elems)

  f32x4 acc[8][4] = {};
  bf16x8 afA[4], afB[4], bfA[4], bfB[4];

#define STAGE_A(T, H)                                                         \
  do {                                                                        \
    _Pragma("unroll") for (int i_ = 0; i_ < 2; ++i_) {                        \
      const int rg_ = (H) * 128 + wave * 16 + i_ * 8;                         \
      load_lds16(A + (size_t)(m0 + rg_ + sgrow) * K + (T) * 64 + sgchunk,     \
                 &As[(T) & 1][rg_ * 64]);                                     \
    }                                                                         \
  } while (0)
#define STAGE_B(T, H)                                                         \
  do {                                                                        \
    _Pragma("unroll") for (int i_ = 0; i_ < 2; ++i_) {                        \
      const int rg_ = (H) * 128 + wave * 16 + i_ * 8;                         \
      load_lds16(B + (size_t)(n0 + rg_ + sgrow) * K + (T) * 64 + sgchunk,     \
                 &Bs[(T) & 1][rg_ * 64]);                                     \
    }                                                                         \
  } while (0)
// frag reads: A-frag lane row = frag_row0 + (lane&15), k = s*32 + quad*8 + [0,8)
// chunk = s*4+quad, XOR-unswizzle with row&7 (= lx&7 since rows are 16-aligned)
#define READ_AF(dst, QM, S)                                                   \
  _Pragma("unroll") for (int mm = 0; mm < 4; ++mm)                            \
    dst[mm] = dsr16(curA + (wr * 128 + ((QM) * 4 + mm) * 16 + lx) * 64        \
                    + ((((S) * 4 + quad) ^ (lx & 7)) * 8));
#define READ_BF(dst, S)                                                       \
  _Pragma("unroll") for (int nn = 0; nn < 4; ++nn)                            \
    dst[nn] = dsr16(curB + (wc * 64 + nn * 16 + lx) * 64                      \
                    + ((((S) * 4 + quad) ^ (lx & 7)) * 8));
// one C-quadrant (16 MFMA, all independent: distinct acc cells)
#define MFMA16(M0, av, bv)                                                    \
  __builtin_amdgcn_s_setprio(1);                                              \
  _Pragma("unroll") for (int mm = 0; mm < 4; ++mm)                            \
  _Pragma("unroll") for (int nn = 0; nn < 4; ++nn)                            \
    acc[(M0) + mm][nn] = __builtin_amdgcn_mfma_f32_16x16x32_bf16(             \
        av[mm], bv[nn], acc[(M0) + mm][nn], 0, 0, 0);                         \
  __builtin_amdgcn_s_setprio(0);

  // prologue: A(0) both halves, B(0) both halves, B(1) both halves
  STAGE_A(0, 0); STAGE_A(0, 1); STAGE_B(0, 0); STAGE_B(0, 1);
  if (NT > 1) { STAGE_B(1, 0); STAGE_B(1, 1); }

  for (int t = 0; t < NT; ++t) {
    asm volatile("" ::: "memory");
    if (t == NT - 1) { asm volatile("s_waitcnt vmcnt(0)" ::: "memory"); }
    else             { asm volatile("s_waitcnt vmcnt(4)" ::: "memory"); }
    __builtin_amdgcn_s_barrier();
    asm volatile("" ::: "memory");
    const ushort* curA = As[t & 1];
    const ushort* curB = Bs[t & 1];

    READ_AF(afA, 0, 0); READ_BF(bfA, 0);          // G1 (8)
    READ_AF(afB, 1, 0);                           // G2 (4)
    if (t + 1 < NT) { STAGE_A(t + 1, 0); STAGE_A(t + 1, 1); }
    WAITK(4);                                     // G1 done
    MFMA16(0, afA, bfA);                          // Q1
    READ_AF(afA, 0, 1); READ_BF(bfB, 1);          // G3 (8)
    WAITK(8);                                     // G2 done
    MFMA16(4, afB, bfA);                          // Q2
    READ_AF(afB, 1, 1);                           // G4 (4)
    WAITK(4);                                     // G3 done -> all B[t] reads done
    PBAR();                                       // block-wide certification
    if (t + 2 < NT) { STAGE_B(t + 2, 0); STAGE_B(t + 2, 1); }
    MFMA16(0, afA, bfB);                          // Q3
    WAITK(0);                                     // G4 done
    MFMA16(4, afB, bfB);                          // Q4
  }

  // epilogue: 16x16 C/D layout col=lane&15, row=(lane>>4)*4+reg (m89/m91)
#pragma unroll
  for (int m = 0; m < 8; ++m)
#pragma unroll
    for (int n = 0; n < 4; ++n)
#pragma unroll
      for (int r = 0; r < 4; ++r) {
        const int row = m0 + wr * 128 + m * 16 + quad * 4 + r;
        const int col = n0 + wc * 64 + n * 16 + lx;
        store_out(C + (size_t)row * N + col, acc[m][n][r]);
      }
#undef STAGE_A
#undef STAGE_B
#undef READ_AF
#undef READ_BF
#undef MFMA16
}

// ---------- RoPE in-place on bf16 qkv ----------
__global__ __launch_bounds__(256) void rope_kernel(const int* __restrict__ pos,
                                                   ushort* __restrict__ qkv) {
  const int rid = blockIdx.x * 4 + (threadIdx.x >> 6);
  const int d = threadIdx.x & 63;
  const int t = rid / 40;
  const int hh = rid - t * 40;
  ushort* p = qkv + (size_t)t * 6144 + (hh < 32 ? hh * 128 : 4096 + (hh - 32) * 128);
  const float inv_freq = powf(10000.0f, -(float)d * (1.0f / 64.0f));
  const float fr = (float)pos[t] * inv_freq;
  float sn, cs;
  sincosf(fr, &sn, &cs);
  const float x1 = bf2f(p[d]);
  const float x2 = bf2f(p[d + 64]);
  p[d] = f2bf(x1 * cs - x2 * sn);
  p[d + 64] = f2bf(x2 * cs + x1 * sn);
}

// ---------- fused flash attention (bf16 MFMA, causal GQA) ----------
// grid: 1024 = B(4) * H(32) * PAIR(8). Block = 256 thr = 4 waves.
// Block processes q-tiles (pair) and (15-pair) of 64 rows -> 17 k-tiles each.
__global__ __launch_bounds__(256) void attn_fused(const ushort* __restrict__ qkv,
                                                  ushort* __restrict__ outb) {
  const int bid = blockIdx.x;
  const int pair = bid & 7;
  const int h = (bid >> 3) & 31;
  const int b = bid >> 8;
  const int kvh = h >> 2;                  // G = 4
  const int tid = threadIdx.x, wave = tid >> 6, lane = tid & 63;
  const int quad = lane >> 4, lx = lane & 15;

  __shared__ ushort Ks[64 * 128];   // [key][d], chunk ^= key&7
  __shared__ ushort Vt[128 * 64];   // [d][key], chunk ^= d&7
  __shared__ ushort Ps[64 * 64];    // [qrow][key], chunk ^= qrow&7

  const size_t tb = (size_t)b * 1024;
  const float scale = 0.08838834764831843f;  // 1/sqrt(128)

#pragma unroll
  for (int phase = 0; phase < 2; ++phase) {
    const int qt64 = phase ? (15 - pair) : pair;
    const int qrow0 = qt64 * 64 + wave * 16;

    bf16x8 qf[4];
#pragma unroll
    for (int ks = 0; ks < 4; ++ks)
      qf[ks] = *(const bf16x8*)(qkv + (tb + qrow0 + lx) * 6144 + h * 128 + ks * 32 + quad * 8);

    f32x4 o[8] = {};
    float mst[4], lst[4];
#pragma unroll
    for (int r = 0; r < 4; ++r) { mst[r] = -1e30f; lst[r] = 0.f; }

    const int nkt = qt64 + 1;
    for (int it = 0; it < nkt; ++it) {
      const int kb = it * 64;
      __syncthreads();
#pragma unroll
      for (int i = 0; i < 4; ++i) {
        const int rg = wave * 16 + i * 4;
        const int row = rg + quad;
        load_lds16(qkv + (tb + kb + row) * 6144 + 4096 + kvh * 128 + ((lx ^ (row & 7)) * 8),
                   Ks + rg * 128);
      }
      {
        const ushort* vp = qkv + (tb + kb + lane) * 6144 + 5120 + kvh * 128 + wave * 32;
#pragma unroll
        for (int c = 0; c < 4; ++c) {
          bf16x8 v8 = *(const bf16x8*)(vp + c * 8);
#pragma unroll
          for (int e = 0; e < 8; ++e) {
            const int d = wave * 32 + c * 8 + e;
            Vt[d * 64 + (((lane >> 3) ^ (d & 7)) * 8) + (lane & 7)] = (ushort)v8[e];
          }
        }
      }
      __syncthreads();

      f32x4 s[4] = {};
#pragma unroll
      for (int ks = 0; ks < 4; ++ks) {
        bf16x8 kf[4];
#pragma unroll
        for (int kt = 0; kt < 4; ++kt)
          kf[kt] = *(const bf16x8*)(Ks + (kt * 16 + lx) * 128 + (((ks * 4 + quad) ^ (lx & 7)) * 8));
#pragma unroll
        for (int kt = 0; kt < 4; ++kt)
          s[kt] = __builtin_amdgcn_mfma_f32_16x16x32_bf16(qf[ks], kf[kt], s[kt], 0, 0, 0);
      }

      const bool diag = (kb + 63 > qrow0);
#pragma unroll
      for (int r = 0; r < 4; ++r) {
        const int row = qrow0 + quad * 4 + r;
        float mx = -1e30f;
#pragma unroll
        for (int kt = 0; kt < 4; ++kt) {
          float sv = s[kt][r] * scale;
          if (diag && (kb + kt * 16 + lx > row)) sv = -1e30f;
          s[kt][r] = sv;
          mx = fmaxf(mx, sv);
        }
        mx = fmaxf(mx, __shfl_xor(mx, 1));
        mx = fmaxf(mx, __shfl_xor(mx, 2));
        mx = fmaxf(mx, __shfl_xor(mx, 4));
        mx = fmaxf(mx, __shfl_xor(mx, 8));
        const float mnew = fmaxf(mst[r], mx);
        const float alpha = __expf(mst[r] - mnew);
        mst[r] = mnew;
        float rs = 0.f;
#pragma unroll
        for (int kt = 0; kt < 4; ++kt) {
          const float pv = __expf(s[kt][r] - mnew);
          s[kt][r] = pv;
          rs += pv;
        }
        rs += __shfl_xor(rs, 1); rs += __shfl_xor(rs, 2);
        rs += __shfl_xor(rs, 4); rs += __shfl_xor(rs, 8);
        lst[r] = lst[r] * alpha + rs;
#pragma unroll
        for (int dt = 0; dt < 8; ++dt) o[dt][r] *= alpha;
        const int prow = wave * 16 + quad * 4 + r;
#pragma unroll
        for (int kt = 0; kt < 4; ++kt)
          Ps[prow * 64 + (((kt * 2 + (lx >> 3)) ^ (prow & 7)) * 8) + (lx & 7)] = f2bf(s[kt][r]);
      }
      __syncthreads();

#pragma unroll
      for (int ks2 = 0; ks2 < 2; ++ks2) {
        const int prow = wave * 16 + lx;
        bf16x8 pf = *(const bf16x8*)(Ps + prow * 64 + (((ks2 * 4 + quad) ^ (lx & 7)) * 8));
#pragma unroll
        for (int dt = 0; dt < 8; ++dt) {
          bf16x8 vf = *(const bf16x8*)(Vt + (dt * 16 + lx) * 64 + (((ks2 * 4 + quad) ^ (lx & 7)) * 8));
          o[dt] = __builtin_amdgcn_mfma_f32_16x16x32_bf16(pf, vf, o[dt], 0, 0, 0);
        }
      }
    }

#pragma unroll
    for (int r = 0; r < 4; ++r) {
      const float inv = 1.f / lst[r];
      const int row = qrow0 + quad * 4 + r;
#pragma unroll
      for (int dt = 0; dt < 8; ++dt)
        outb[(tb + row) * 4096 + h * 128 + dt * 16 + lx] = f2bf(o[dt][r] * inv);
    }
  }
}

// ---------- launch ----------
extern "C" void kernel_launch(void* const* d_in, const int* in_sizes, int n_in,
                              void* d_out, int out_size, void* d_ws, size_t ws_size,
                              hipStream_t stream) {
  const int* positions = (const int*)d_in[0];
  const float* hidden  = (const float*)d_in[1];
  const float* w_qkv   = (const float*)d_in[2];
  const float* w_dense = (const float*)d_in[3];
  float* out = (float*)d_out;

  ushort* hidden_bf = (ushort*)d_ws;                         // 4096*4096
  ushort* wqkv_bf   = hidden_bf + (size_t)16777216;          // 6144*4096
  ushort* wdense_bf = wqkv_bf   + (size_t)25165824;          // 4096*4096
  ushort* qkv_bf    = wdense_bf + (size_t)16777216;          // 4096*6144
  ushort* attn_bf   = qkv_bf    + (size_t)25165824;          // 4096*4096

  cast_kernel<<<16384, 256, 0, stream>>>(hidden,  hidden_bf, 4194304);
  cast_kernel<<<24576, 256, 0, stream>>>(w_qkv,   wqkv_bf,   6291456);
  cast_kernel<<<16384, 256, 0, stream>>>(w_dense, wdense_bf, 4194304);

  gemm256<ushort><<<dim3(24, 16), 512, 0, stream>>>(hidden_bf, wqkv_bf, qkv_bf, 4096, 6144, 4096);

  rope_kernel<<<40960, 256, 0, stream>>>(positions, qkv_bf);

  attn_fused<<<1024, 256, 0, stream>>>(qkv_bf, attn_bf);

  gemm256<float><<<dim3(16, 16), 512, 0, stream>>>(attn_bf, wdense_bf, out, 4096, 4096, 4096);
}

// Round 5
// 704.522 us; speedup vs baseline: 1.0804x; 1.0778x over previous
//
#include <hip/hip_runtime.h>

typedef short bf16x8 __attribute__((ext_vector_type(8)));
typedef float f32x4 __attribute__((ext_vector_type(4)));

// ---------- helpers ----------
__device__ __forceinline__ ushort f2bf(float f) {
  union { float f; unsigned u; } x; x.f = f;
  unsigned r = x.u + 0x7fffu + ((x.u >> 16) & 1u);  // RNE
  return (ushort)(r >> 16);
}
__device__ __forceinline__ float bf2f(ushort u) {
  union { unsigned u; float f; } x; x.u = ((unsigned)u) << 16; return x.f;
}
__device__ __forceinline__ void load_lds16(const void* g, void* l) {
  __builtin_amdgcn_global_load_lds((const __attribute__((address_space(1))) void*)g,
                                   (__attribute__((address_space(3))) void*)l, 16, 0, 0);
}
// asm ds_read_b128: hides the LDS RAW dependence on global_load_lds from the
// compiler (no conservative vmcnt drains). Ordering enforced ONLY by explicit
// barriers + counted lgkmcnt + sched_barrier fences.
typedef __attribute__((address_space(3))) const ushort* lds_cp;
__device__ __forceinline__ bf16x8 dsr16(const ushort* p) {
  bf16x8 r;
  asm volatile("ds_read_b128 %0, %1" : "=v"(r) : "v"((lds_cp)p));
  return r;
}
__device__ __forceinline__ void store_out(float* p, float v) { *p = v; }
__device__ __forceinline__ void store_out(ushort* p, float v) { *p = f2bf(v); }

// ---------- fp32 -> bf16 cast ----------
__global__ __launch_bounds__(256) void cast_kernel(const float* __restrict__ in,
                                                   ushort* __restrict__ out, int n4) {
  int i = blockIdx.x * 256 + threadIdx.x;
  if (i < n4) {
    float4 v = ((const float4*)in)[i];
    ushort4 o;
    o.x = f2bf(v.x); o.y = f2bf(v.y); o.z = f2bf(v.z); o.w = f2bf(v.w);
    ((ushort4*)out)[i] = o;
  }
}

// ---------- 256x256 NT GEMM, counted-lgkm JIT pipeline (round-4 best) ----------
#define PBAR() do { asm volatile("" ::: "memory"); __builtin_amdgcn_s_barrier(); \
                    asm volatile("" ::: "memory"); } while (0)
#define WAITK(n) do { asm volatile("s_waitcnt lgkmcnt(" #n ")" ::: "memory"); \
                      __builtin_amdgcn_sched_barrier(0); } while (0)

template <typename OutT>
__global__ __launch_bounds__(512) void gemm256(const ushort* __restrict__ A,
                                               const ushort* __restrict__ B,
                                               OutT* __restrict__ C,
                                               int M, int N, int K) {
  __shared__ ushort As[2][256 * 64];
  __shared__ ushort Bs[2][256 * 64];
  const int tid = threadIdx.x;
  const int wave = tid >> 6, lane = tid & 63;
  const int quad = lane >> 4, lx = lane & 15;
  const int wr = wave >> 2, wc = wave & 3;
  const int m0 = blockIdx.y * 256, n0 = blockIdx.x * 256;
  const int NT = K >> 6;
  const int sgrow = lane >> 3;                 // row within 8-row group
  const int sgchunk = ((lane & 7) ^ sgrow) * 8;  // swizzled global chunk (elems)

  f32x4 acc[8][4] = {};
  bf16x8 afA[4], afB[4], bfA[4], bfB[4];

#define STAGE_A(T, H)                                                         \
  do {                                                                        \
    _Pragma("unroll") for (int i_ = 0; i_ < 2; ++i_) {                        \
      const int rg_ = (H) * 128 + wave * 16 + i_ * 8;                         \
      load_lds16(A + (size_t)(m0 + rg_ + sgrow) * K + (T) * 64 + sgchunk,     \
                 &As[(T) & 1][rg_ * 64]);                                     \
    }                                                                         \
  } while (0)
#define STAGE_B(T, H)                                                         \
  do {                                                                        \
    _Pragma("unroll") for (int i_ = 0; i_ < 2; ++i_) {                        \
      const int rg_ = (H) * 128 + wave * 16 + i_ * 8;                         \
      load_lds16(B + (size_t)(n0 + rg_ + sgrow) * K + (T) * 64 + sgchunk,     \
                 &Bs[(T) & 1][rg_ * 64]);                                     \
    }                                                                         \
  } while (0)
#define READ_AF(dst, QM, S)                                                   \
  _Pragma("unroll") for (int mm = 0; mm < 4; ++mm)                            \
    dst[mm] = dsr16(curA + (wr * 128 + ((QM) * 4 + mm) * 16 + lx) * 64        \
                    + ((((S) * 4 + quad) ^ (lx & 7)) * 8));
#define READ_BF(dst, S)                                                       \
  _Pragma("unroll") for (int nn = 0; nn < 4; ++nn)                            \
    dst[nn] = dsr16(curB + (wc * 64 + nn * 16 + lx) * 64                      \
                    + ((((S) * 4 + quad) ^ (lx & 7)) * 8));
#define MFMA16(M0, av, bv)                                                    \
  __builtin_amdgcn_s_setprio(1);                                              \
  _Pragma("unroll") for (int mm = 0; mm < 4; ++mm)                            \
  _Pragma("unroll") for (int nn = 0; nn < 4; ++nn)                            \
    acc[(M0) + mm][nn] = __builtin_amdgcn_mfma_f32_16x16x32_bf16(             \
        av[mm], bv[nn], acc[(M0) + mm][nn], 0, 0, 0);                         \
  __builtin_amdgcn_s_setprio(0);

  STAGE_A(0, 0); STAGE_A(0, 1); STAGE_B(0, 0); STAGE_B(0, 1);
  if (NT > 1) { STAGE_B(1, 0); STAGE_B(1, 1); }

  for (int t = 0; t < NT; ++t) {
    asm volatile("" ::: "memory");
    if (t == NT - 1) { asm volatile("s_waitcnt vmcnt(0)" ::: "memory"); }
    else             { asm volatile("s_waitcnt vmcnt(4)" ::: "memory"); }
    __builtin_amdgcn_s_barrier();
    asm volatile("" ::: "memory");
    const ushort* curA = As[t & 1];
    const ushort* curB = Bs[t & 1];

    READ_AF(afA, 0, 0); READ_BF(bfA, 0);          // G1 (8)
    READ_AF(afB, 1, 0);                           // G2 (4)
    if (t + 1 < NT) { STAGE_A(t + 1, 0); STAGE_A(t + 1, 1); }
    WAITK(4);                                     // G1 done
    MFMA16(0, afA, bfA);                          // Q1
    READ_AF(afA, 0, 1); READ_BF(bfB, 1);          // G3 (8)
    WAITK(8);                                     // G2 done
    MFMA16(4, afB, bfA);                          // Q2
    READ_AF(afB, 1, 1);                           // G4 (4)
    WAITK(4);                                     // G3 done -> all B[t] reads done
    PBAR();                                       // block-wide certification
    if (t + 2 < NT) { STAGE_B(t + 2, 0); STAGE_B(t + 2, 1); }
    MFMA16(0, afA, bfB);                          // Q3
    WAITK(0);                                     // G4 done
    MFMA16(4, afB, bfB);                          // Q4
  }

#pragma unroll
  for (int m = 0; m < 8; ++m)
#pragma unroll
    for (int n = 0; n < 4; ++n)
#pragma unroll
      for (int r = 0; r < 4; ++r) {
        const int row = m0 + wr * 128 + m * 16 + quad * 4 + r;
        const int col = n0 + wc * 64 + n * 16 + lx;
        store_out(C + (size_t)row * N + col, acc[m][n][r]);
      }
#undef STAGE_A
#undef STAGE_B
#undef READ_AF
#undef READ_BF
#undef MFMA16
}

// ---------- RoPE in-place on bf16 qkv ----------
__global__ __launch_bounds__(256) void rope_kernel(const int* __restrict__ pos,
                                                   ushort* __restrict__ qkv) {
  const int rid = blockIdx.x * 4 + (threadIdx.x >> 6);
  const int d = threadIdx.x & 63;
  const int t = rid / 40;
  const int hh = rid - t * 40;
  ushort* p = qkv + (size_t)t * 6144 + (hh < 32 ? hh * 128 : 4096 + (hh - 32) * 128);
  // powf(10000, -d/64) = exp2(-d * log2(10000)/64)
  const float inv_freq = exp2f((float)d * -0.20762050593046f);
  const float fr = (float)pos[t] * inv_freq;
  float sn, cs;
  sincosf(fr, &sn, &cs);
  const float x1 = bf2f(p[d]);
  const float x2 = bf2f(p[d + 64]);
  p[d] = f2bf(x1 * cs - x2 * sn);
  p[d + 64] = f2bf(x2 * cs + x1 * sn);
}

// ---------- V transpose: qkv V-region -> Vt_g[b][kvh][d][key] ----------
// One-time transpose so attention can stage V^T tiles with global_load_lds
// instead of per-tile scalar LDS transposes. grid (16 key-tiles, 32 b*kvh).
__global__ __launch_bounds__(256) void vtrans_kernel(const ushort* __restrict__ qkv,
                                                     ushort* __restrict__ vtg) {
  __shared__ ushort T[64][136];  // 64 keys x 128 d, stride 136 keeps 16B align
  const int kt = blockIdx.x, bh = blockIdx.y;
  const int b = bh >> 3, kvh = bh & 7;
  const int t = threadIdx.x;
  const size_t tb = (size_t)b * 1024;
  const int kb = kt * 64;
  // load: 1024 chunks of 8 elems; chunk c: key=c>>4, d0=(c&15)*8 (coalesced)
#pragma unroll
  for (int i = 0; i < 4; ++i) {
    const int c = i * 256 + t;
    const int key = c >> 4, d0 = (c & 15) * 8;
    *(bf16x8*)&T[key][d0] =
        *(const bf16x8*)(qkv + (tb + kb + key) * 6144 + 5120 + kvh * 128 + d0);
  }
  __syncthreads();
  // store transposed: thread (d = t>>1, half = t&1) writes 32 consecutive keys
  const int d = t >> 1, half = t & 1;
#pragma unroll
  for (int j = 0; j < 4; ++j) {
    const int k0 = half * 32 + j * 8;
    bf16x8 v;
#pragma unroll
    for (int e = 0; e < 8; ++e) v[e] = (short)T[k0 + e][d];
    *(bf16x8*)(vtg + ((size_t)bh * 128 + d) * 1024 + kb + k0) = v;
  }
}

// ---------- fused flash attention (bf16 MFMA, causal GQA) ----------
// grid: 1024 = B(4) * H(32) * PAIR(8). Block = 256 thr = 4 waves.
// Block processes q-tiles (pair) and (15-pair) of 64 rows -> 17 k-tiles each.
// V^T comes pre-transposed from vtrans_kernel; both K and Vt tiles are staged
// with global_load_lds (linear dest, XOR-swizzled source chunk).
__global__ __launch_bounds__(256) void attn_fused(const ushort* __restrict__ qkv,
                                                  const ushort* __restrict__ vtg,
                                                  ushort* __restrict__ outb) {
  const int bid = blockIdx.x;
  const int pair = bid & 7;
  const int h = (bid >> 3) & 31;
  const int b = bid >> 8;
  const int kvh = h >> 2;                  // G = 4
  const int tid = threadIdx.x, wave = tid >> 6, lane = tid & 63;
  const int quad = lane >> 4, lx = lane & 15;

  __shared__ ushort Ks[64 * 128];   // [key][d], chunk ^= key&7
  __shared__ ushort Vt[128 * 64];   // [d][key], chunk ^= d&7
  __shared__ ushort Ps[64 * 64];    // [qrow][key], chunk ^= qrow&7

  const size_t tb = (size_t)b * 1024;
  const ushort* vbase = vtg + (size_t)(b * 8 + kvh) * 131072;  // 128*1024
  const float scale = 0.08838834764831843f;  // 1/sqrt(128)

#pragma unroll
  for (int phase = 0; phase < 2; ++phase) {
    const int qt64 = phase ? (15 - pair) : pair;
    const int qrow0 = qt64 * 64 + wave * 16;

    bf16x8 qf[4];
#pragma unroll
    for (int ks = 0; ks < 4; ++ks)
      qf[ks] = *(const bf16x8*)(qkv + (tb + qrow0 + lx) * 6144 + h * 128 + ks * 32 + quad * 8);

    f32x4 o[8] = {};
    float mst[4], lst[4];
#pragma unroll
    for (int r = 0; r < 4; ++r) { mst[r] = -1e30f; lst[r] = 0.f; }

    const int nkt = qt64 + 1;
    for (int it = 0; it < nkt; ++it) {
      const int kb = it * 64;
      __syncthreads();
      // K tile: 16 rows/wave, 4 rows per gload (row len 128 elems = 16 chunks)
#pragma unroll
      for (int i = 0; i < 4; ++i) {
        const int rg = wave * 16 + i * 4;
        const int row = rg + quad;
        load_lds16(qkv + (tb + kb + row) * 6144 + 4096 + kvh * 128 + ((lx ^ (row & 7)) * 8),
                   Ks + rg * 128);
      }
      // V^T tile: 32 rows/wave, 8 rows per gload (row len 64 elems = 8 chunks)
#pragma unroll
      for (int i = 0; i < 4; ++i) {
        const int rg = wave * 32 + i * 8;
        const int row = rg + (lane >> 3);
        load_lds16(vbase + (size_t)row * 1024 + kb + (((lane & 7) ^ (row & 7)) * 8),
                   Vt + rg * 64);
      }
      __syncthreads();

      f32x4 s[4] = {};
#pragma unroll
      for (int ks = 0; ks < 4; ++ks) {
        bf16x8 kf[4];
#pragma unroll
        for (int kt = 0; kt < 4; ++kt)
          kf[kt] = *(const bf16x8*)(Ks + (kt * 16 + lx) * 128 + (((ks * 4 + quad) ^ (lx & 7)) * 8));
#pragma unroll
        for (int kt = 0; kt < 4; ++kt)
          s[kt] = __builtin_amdgcn_mfma_f32_16x16x32_bf16(qf[ks], kf[kt], s[kt], 0, 0, 0);
      }

      const bool diag = (kb + 63 > qrow0);
#pragma unroll
      for (int r = 0; r < 4; ++r) {
        const int row = qrow0 + quad * 4 + r;
        float mx = -1e30f;
#pragma unroll
        for (int kt = 0; kt < 4; ++kt) {
          float sv = s[kt][r] * scale;
          if (diag && (kb + kt * 16 + lx > row)) sv = -1e30f;
          s[kt][r] = sv;
          mx = fmaxf(mx, sv);
        }
        mx = fmaxf(mx, __shfl_xor(mx, 1));
        mx = fmaxf(mx, __shfl_xor(mx, 2));
        mx = fmaxf(mx, __shfl_xor(mx, 4));
        mx = fmaxf(mx, __shfl_xor(mx, 8));
        const float mnew = fmaxf(mst[r], mx);
        const float alpha = __expf(mst[r] - mnew);
        mst[r] = mnew;
        float rs = 0.f;
#pragma unroll
        for (int kt = 0; kt < 4; ++kt) {
          const float pv = __expf(s[kt][r] - mnew);
          s[kt][r] = pv;
          rs += pv;
        }
        rs += __shfl_xor(rs, 1); rs += __shfl_xor(rs, 2);
        rs += __shfl_xor(rs, 4); rs += __shfl_xor(rs, 8);
        lst[r] = lst[r] * alpha + rs;
#pragma unroll
        for (int dt = 0; dt < 8; ++dt) o[dt][r] *= alpha;
        const int prow = wave * 16 + quad * 4 + r;
#pragma unroll
        for (int kt = 0; kt < 4; ++kt)
          Ps[prow * 64 + (((kt * 2 + (lx >> 3)) ^ (prow & 7)) * 8) + (lx & 7)] = f2bf(s[kt][r]);
      }
      __syncthreads();

#pragma unroll
      for (int ks2 = 0; ks2 < 2; ++ks2) {
        const int prow = wave * 16 + lx;
        bf16x8 pf = *(const bf16x8*)(Ps + prow * 64 + (((ks2 * 4 + quad) ^ (lx & 7)) * 8));
#pragma unroll
        for (int dt = 0; dt < 8; ++dt) {
          bf16x8 vf = *(const bf16x8*)(Vt + (dt * 16 + lx) * 64 + (((ks2 * 4 + quad) ^ (lx & 7)) * 8));
          o[dt] = __builtin_amdgcn_mfma_f32_16x16x32_bf16(pf, vf, o[dt], 0, 0, 0);
        }
      }
    }

#pragma unroll
    for (int r = 0; r < 4; ++r) {
      const float inv = 1.f / lst[r];
      const int row = qrow0 + quad * 4 + r;
#pragma unroll
      for (int dt = 0; dt < 8; ++dt)
        outb[(tb + row) * 4096 + h * 128 + dt * 16 + lx] = f2bf(o[dt][r] * inv);
    }
  }
}

// ---------- launch ----------
extern "C" void kernel_launch(void* const* d_in, const int* in_sizes, int n_in,
                              void* d_out, int out_size, void* d_ws, size_t ws_size,
                              hipStream_t stream) {
  const int* positions = (const int*)d_in[0];
  const float* hidden  = (const float*)d_in[1];
  const float* w_qkv   = (const float*)d_in[2];
  const float* w_dense = (const float*)d_in[3];
  float* out = (float*)d_out;

  ushort* hidden_bf = (ushort*)d_ws;                         // 4096*4096
  ushort* wqkv_bf   = hidden_bf + (size_t)16777216;          // 6144*4096
  ushort* wdense_bf = wqkv_bf   + (size_t)25165824;          // 4096*4096
  ushort* qkv_bf    = wdense_bf + (size_t)16777216;          // 4096*6144
  ushort* attn_bf   = qkv_bf    + (size_t)25165824;          // 4096*4096
  // hidden_bf is dead after the QKV GEMM -> reuse it for V^T (needs 4.2M elems)
  ushort* vt_g      = hidden_bf;

  cast_kernel<<<16384, 256, 0, stream>>>(hidden,  hidden_bf, 4194304);
  cast_kernel<<<24576, 256, 0, stream>>>(w_qkv,   wqkv_bf,   6291456);
  cast_kernel<<<16384, 256, 0, stream>>>(w_dense, wdense_bf, 4194304);

  gemm256<ushort><<<dim3(24, 16), 512, 0, stream>>>(hidden_bf, wqkv_bf, qkv_bf, 4096, 6144, 4096);

  rope_kernel<<<40960, 256, 0, stream>>>(positions, qkv_bf);

  vtrans_kernel<<<dim3(16, 32), 256, 0, stream>>>(qkv_bf, vt_g);

  attn_fused<<<1024, 256, 0, stream>>>(qkv_bf, vt_g, attn_bf);

  gemm256<float><<<dim3(16, 16), 512, 0, stream>>>(attn_bf, wdense_bf, out, 4096, 4096, 4096);
}